// Round 7
// baseline (515.882 us; speedup 1.0000x reference)
//
#include <hip/hip_runtime.h>
#include <hip/hip_bf16.h>
#include <math.h>
#include <stdint.h>

// Problem constants
static constexpr int Bb = 8, S = 1024, E = 1152, H = 16, D = 72;
static constexpr int N3 = 3 * E;                 // 3456
static constexpr long QKV_T = (long)Bb * H * S * D;  // 9437184 elems per tensor

typedef __attribute__((ext_vector_type(8))) short bf16x8;
typedef __attribute__((ext_vector_type(4))) short bf16x4;
typedef __attribute__((ext_vector_type(4))) float f32x4;

#define MFMA16(A, B, C) __builtin_amdgcn_mfma_f32_16x16x32_bf16(A, B, C, 0, 0, 0)

__device__ __forceinline__ short f2bf(float f) {
    __hip_bfloat16 h = __float2bfloat16(f);
    return __builtin_bit_cast(short, h);
}
__device__ __forceinline__ float bf2f(short s) {
    unsigned u = ((unsigned)(unsigned short)s) << 16;
    return __builtin_bit_cast(float, u);
}
__device__ __forceinline__ unsigned packbf(float lo, float hi) {
    return (unsigned)(unsigned short)f2bf(lo) | ((unsigned)(unsigned short)f2bf(hi) << 16);
}

__device__ __forceinline__ void gload_lds16(const void* g, void* l) {
    __builtin_amdgcn_global_load_lds(
        (const __attribute__((address_space(1))) unsigned int*)g,
        (__attribute__((address_space(3))) unsigned int*)l, 16, 0, 0);
}

// ---------------------------------------------------------------------------
// Kernel A: transpose+convert.  W[K][N] f32 -> WT[N][K] bf16.
// ---------------------------------------------------------------------------
__global__ __launch_bounds__(256)
void wt_conv(const float* __restrict__ W, short* __restrict__ WT, int K, int N)
{
    __shared__ float tt[32][33];
    const int n0 = blockIdx.x * 32, k0 = blockIdx.y * 32;
    const int t = threadIdx.x;
    {
        int r = t >> 3, c4 = (t & 7) * 4;
        float4 v = *reinterpret_cast<const float4*>(W + (long)(k0 + r) * N + n0 + c4);
        tt[r][c4 + 0] = v.x; tt[r][c4 + 1] = v.y; tt[r][c4 + 2] = v.z; tt[r][c4 + 3] = v.w;
    }
    __syncthreads();
    {
        int n = t >> 3, k4 = (t & 7) * 4;
        bf16x4 o = {f2bf(tt[k4 + 0][n]), f2bf(tt[k4 + 1][n]),
                    f2bf(tt[k4 + 2][n]), f2bf(tt[k4 + 3][n])};
        *reinterpret_cast<bf16x4*>(WT + (long)(n0 + n) * K + k0 + k4) = o;
    }
}

// ---------------------------------------------------------------------------
// Kernel B: split f32 -> hi/lo bf16.  n4 = element_count / 4.
// ---------------------------------------------------------------------------
__global__ __launch_bounds__(256)
void presplit(const float* __restrict__ X, short* __restrict__ XH,
              short* __restrict__ XL, long n4)
{
    for (long i = (long)blockIdx.x * 256 + threadIdx.x; i < n4; i += (long)gridDim.x * 256) {
        float4 v = reinterpret_cast<const float4*>(X)[i];
        short h0 = f2bf(v.x), h1 = f2bf(v.y), h2 = f2bf(v.z), h3 = f2bf(v.w);
        bf16x4 hi = {h0, h1, h2, h3};
        bf16x4 lo = {f2bf(v.x - bf2f(h0)), f2bf(v.y - bf2f(h1)),
                     f2bf(v.z - bf2f(h2)), f2bf(v.w - bf2f(h3))};
        reinterpret_cast<bf16x4*>(XH)[i] = hi;
        reinterpret_cast<bf16x4*>(XL)[i] = lo;
    }
}

// ---------------------------------------------------------------------------
// Kernel 1: projection for ONE of q/k/v.  C[rows,1152] = X @ Wg + bg.
// 2-term split-bf16 (Ahi*B + Alo*B); full-wave global_load_lds staging only.
// which==2 (V): stored transposed [bh][d][s] (linear, for direct A-frag reads).
// ---------------------------------------------------------------------------
__global__ __launch_bounds__(256)
void qkv_proj_one(const short* __restrict__ XH, const short* __restrict__ XL,
                  const short* __restrict__ WTn, const float* __restrict__ bias,
                  short* __restrict__ qkvW, int which, int m_base)
{
    __shared__ short aHi[128][32], aLo[128][32], bW[128][32];
    const int tid = threadIdx.x, lane = tid & 63, w = tid >> 6;
    const int c = lane & 15, g = lane >> 4;
    const int m0 = blockIdx.y * 128, n0 = blockIdx.x * 128;
    const int wm = (w >> 1) * 64, wn = (w & 1) * 64;
    const int lrow = lane >> 2, lch = (lane & 3) * 8;

    f32x4 acc[4][4] = {};

    for (int k0 = 0; k0 < E; k0 += 32) {
        __syncthreads();
        for (int t = 0; t < 2; ++t) {
            int row = w * 32 + t * 16;
            gload_lds16(XH + (long)(m0 + row + lrow) * E + k0 + lch, &aHi[row][0]);
            gload_lds16(XL + (long)(m0 + row + lrow) * E + k0 + lch, &aLo[row][0]);
            gload_lds16(WTn + (long)(n0 + row + lrow) * E + k0 + lch, &bW[row][0]);
        }
        __syncthreads();

        bf16x8 ah[4], al[4], bh[4];
        for (int i = 0; i < 4; ++i) {
            ah[i] = *reinterpret_cast<const bf16x8*>(&aHi[wm + i * 16 + c][g * 8]);
            al[i] = *reinterpret_cast<const bf16x8*>(&aLo[wm + i * 16 + c][g * 8]);
            bh[i] = *reinterpret_cast<const bf16x8*>(&bW[wn + i * 16 + c][g * 8]);
        }
        for (int i = 0; i < 4; ++i)
            for (int j = 0; j < 4; ++j) {
                acc[i][j] = MFMA16(ah[i], bh[j], acc[i][j]);
                acc[i][j] = MFMA16(al[i], bh[j], acc[i][j]);
            }
    }

    for (int j = 0; j < 4; ++j) {
        int n = n0 + wn + j * 16 + c;      // 0..1151
        float bv = bias[n];
        int hh = n / D, dd = n % D;
        if (which < 2) {
            for (int i = 0; i < 4; ++i) {
                int rowb = m_base + m0 + wm + i * 16 + g * 4;
                for (int r = 0; r < 4; ++r) {
                    int row = rowb + r;
                    int b = row >> 10, s = row & 1023;
                    qkvW[((long)(b * H + hh) * S + s) * D + dd] = f2bf(acc[i][j][r] + bv);
                }
            }
        } else {
            for (int i = 0; i < 4; ++i) {
                int srow = m_base + m0 + wm + i * 16 + g * 4;   // 4 consecutive s
                int b = srow >> 10, s = srow & 1023;
                bf16x4 pk = {f2bf(acc[i][j][0] + bv), f2bf(acc[i][j][1] + bv),
                             f2bf(acc[i][j][2] + bv), f2bf(acc[i][j][3] + bv)};
                *reinterpret_cast<bf16x4*>(&qkvW[((long)(b * H + hh) * D + dd) * S + s]) = pk;
            }
        }
    }
}

// ---------------------------------------------------------------------------
// Kernel 2: flash attention, swapped-operand form.  No KV LDS, no barriers:
// K and V^T are L2-resident (147 KB per (b,h), reused by 8 blocks) and read
// directly into MFMA A-fragments.  S^T = K*Q^T puts each q-row's scores
// lane-local (16 per i-tile) -> in-lane softmax (2 shfls).  P packed to
// bf16-pair dwords in a small per-wave LDS buffer, read back as B-frags for
// O^T = V^T * P^T.  Output rows d>=72 are garbage and masked on store.
// ---------------------------------------------------------------------------
__global__ __launch_bounds__(256, 4)
void attn_fwd(const short* __restrict__ qkv, short* __restrict__ attn)
{
    __shared__ unsigned p_t[4][2][16][36];   // [wave][i][q=c][kpair] (+pad)
    const int tid = threadIdx.x, lane = tid & 63, w = tid >> 6;
    const int c = lane & 15, g = lane >> 4;
    const int q0 = blockIdx.x * 128;
    const int bh = blockIdx.y;
    const int b = bh >> 4, h = bh & 15;

    const short* Qb = qkv + (long)bh * (S * D);
    const short* Kb = qkv + QKV_T + (long)bh * (S * D);
    const short* Vt = qkv + 2 * QKV_T + (long)bh * ((long)D * S);

    // Q fragments (used as B operand; identical lane layout to A), tail zero
    bf16x8 qf[2][3];
    const bf16x8 zf = {};
    for (int i = 0; i < 2; ++i) {
        const short* qr = Qb + (long)(q0 + w * 32 + i * 16 + c) * D;
        qf[i][0] = *reinterpret_cast<const bf16x8*>(qr + g * 8);
        qf[i][1] = *reinterpret_cast<const bf16x8*>(qr + 32 + g * 8);
        qf[i][2] = (g == 0) ? *reinterpret_cast<const bf16x8*>(qr + 64) : zf;
    }

    const float K2 = 0.17003594880664552f;   // 72^-0.5 * log2(e)
    float m_run[2] = {-1e30f, -1e30f}, l_run[2] = {0.f, 0.f};
    f32x4 accO[5][2] = {};

    for (int kt = 0; kt < 16; ++kt) {
        // ---- S^T[k'][q] = K Q^T ----
        f32x4 sT[4][2] = {};
        for (int dc = 0; dc < 3; ++dc) {
            for (int j = 0; j < 4; ++j) {
                bf16x8 kf = *reinterpret_cast<const bf16x8*>(
                    Kb + (long)(kt * 64 + j * 16 + c) * D + dc * 32 + g * 8);
                for (int i = 0; i < 2; ++i)
                    sT[j][i] = MFMA16(kf, qf[i][dc], sT[j][i]);
            }
        }

        // ---- in-lane online softmax (per i: one q-row per lane) ----
        for (int i = 0; i < 2; ++i) {
            float mx = -1e30f;
            for (int j = 0; j < 4; ++j)
                for (int r = 0; r < 4; ++r) mx = fmaxf(mx, sT[j][i][r]);
            mx = fmaxf(mx, __shfl_xor(mx, 16));
            mx = fmaxf(mx, __shfl_xor(mx, 32));
            float m_new = fmaxf(m_run[i], mx);
            float corr = exp2f((m_run[i] - m_new) * K2);
            float mh = m_new * K2;
            m_run[i] = m_new;
            float ps = 0.f;
            for (int j = 0; j < 4; ++j) {
                float p0 = exp2f(fmaf(sT[j][i][0], K2, -mh));
                float p1 = exp2f(fmaf(sT[j][i][1], K2, -mh));
                float p2 = exp2f(fmaf(sT[j][i][2], K2, -mh));
                float p3 = exp2f(fmaf(sT[j][i][3], K2, -mh));
                ps += (p0 + p1) + (p2 + p3);
                p_t[w][i][c][j * 8 + g * 2 + 0] = packbf(p0, p1);
                p_t[w][i][c][j * 8 + g * 2 + 1] = packbf(p2, p3);
            }
            ps += __shfl_xor(ps, 16);
            ps += __shfl_xor(ps, 32);
            l_run[i] = l_run[i] * corr + ps;
            for (int n = 0; n < 5; ++n)
                for (int r = 0; r < 4; ++r) accO[n][i][r] *= corr;
        }

        // ---- O^T[d][q] += V^T P^T ----
        for (int ks = 0; ks < 2; ++ks) {
            bf16x8 pf[2];
            for (int i = 0; i < 2; ++i)
                pf[i] = *reinterpret_cast<const bf16x8*>(&p_t[w][i][c][ks * 16 + g * 4]);
            for (int n = 0; n < 5; ++n) {
                bf16x8 vf = *reinterpret_cast<const bf16x8*>(
                    Vt + (long)(n * 16 + c) * S + kt * 64 + ks * 32 + g * 8);
                for (int i = 0; i < 2; ++i)
                    accO[n][i] = MFMA16(vf, pf[i], accO[n][i]);
            }
        }
    }

    // ---- epilogue: attn[q][h*72+d], mask d >= 72, packed 4-short stores ----
    for (int i = 0; i < 2; ++i) {
        float inv = 1.f / l_run[i];
        int q = q0 + w * 32 + i * 16 + c;
        for (int n = 0; n < 5; ++n) {
            int d0 = n * 16 + g * 4;
            if (d0 >= D) continue;
            bf16x4 pk = {f2bf(accO[n][i][0] * inv), f2bf(accO[n][i][1] * inv),
                         f2bf(accO[n][i][2] * inv), f2bf(accO[n][i][3] * inv)};
            *reinterpret_cast<bf16x4*>(attn + (long)(b * S + q) * E + h * D + d0) = pk;
        }
    }
}

// ---------------------------------------------------------------------------
// Kernel 3: out projection.  out[8192,1152] = attn(bf16) @ WTo(bf16) + b.
// ---------------------------------------------------------------------------
__global__ __launch_bounds__(256)
void out_proj(const short* __restrict__ Aat, const short* __restrict__ WTo,
              const float* __restrict__ bias, float* __restrict__ out)
{
    __shared__ short aT[128][32], bT[128][32];
    const int tid = threadIdx.x, lane = tid & 63, w = tid >> 6;
    const int c = lane & 15, g = lane >> 4;
    const int m0 = blockIdx.y * 128, n0 = blockIdx.x * 128;
    const int wm = (w >> 1) * 64, wn = (w & 1) * 64;
    const int lrow = lane >> 2, lch = (lane & 3) * 8;

    f32x4 acc[4][4] = {};
    for (int k0 = 0; k0 < E; k0 += 32) {
        __syncthreads();
        for (int t = 0; t < 2; ++t) {
            int row = w * 32 + t * 16;
            gload_lds16(Aat + (long)(m0 + row + lrow) * E + k0 + lch, &aT[row][0]);
            gload_lds16(WTo + (long)(n0 + row + lrow) * E + k0 + lch, &bT[row][0]);
        }
        __syncthreads();

        bf16x8 af[4], bf[4];
        for (int i = 0; i < 4; ++i) {
            af[i] = *reinterpret_cast<const bf16x8*>(&aT[wm + i * 16 + c][g * 8]);
            bf[i] = *reinterpret_cast<const bf16x8*>(&bT[wn + i * 16 + c][g * 8]);
        }
        for (int i = 0; i < 4; ++i)
            for (int j = 0; j < 4; ++j)
                acc[i][j] = MFMA16(af[i], bf[j], acc[i][j]);
    }

    for (int j = 0; j < 4; ++j) {
        int n = n0 + wn + j * 16 + c;
        float bv = bias[n];
        for (int i = 0; i < 4; ++i)
            for (int r = 0; r < 4; ++r) {
                int row = m0 + wm + i * 16 + g * 4 + r;
                out[(long)row * E + n] = acc[i][j][r] + bv;
            }
    }
}

// ---------------------------------------------------------------------------
// Workspace (shorts), peak 83.46 MB:
//   Q[QKV_T] | K[QKV_T] | V^T[QKV_T] | A[QKV_T] | WT[3456*1152]
// ---------------------------------------------------------------------------
extern "C" void kernel_launch(void* const* d_in, const int* in_sizes, int n_in,
                              void* d_out, int out_size, void* d_ws, size_t ws_size,
                              hipStream_t stream)
{
    const float* qin   = (const float*)d_in[0];
    const float* kin   = (const float*)d_in[1];
    const float* vin   = (const float*)d_in[2];
    const float* w_in  = (const float*)d_in[3];
    const float* b_in  = (const float*)d_in[4];
    const float* w_out = (const float*)d_in[5];
    const float* b_out = (const float*)d_in[6];

    short* ws  = (short*)d_ws;
    short* Q   = ws;
    short* K   = ws + QKV_T;
    short* V   = ws + 2 * QKV_T;
    short* A   = ws + 3 * QKV_T;
    short* WT  = ws + 4 * QKV_T;
    short* WTo = WT;
    float* out = (float*)d_out;
    const long HALF = QKV_T / 2;

    wt_conv<<<dim3(108, 36), 256, 0, stream>>>(w_in, WT, E, N3);

    // V (which=2): hi/lo in Q,K slots (free)
    presplit<<<2048, 256, 0, stream>>>(vin, Q, K, QKV_T / 4);
    qkv_proj_one<<<dim3(9, 64), 256, 0, stream>>>(Q, K, WT + 2L * E * E, b_in + 2 * E, V, 2, 0);
    // K (which=1): hi in Q slot, lo in A slot
    presplit<<<2048, 256, 0, stream>>>(kin, Q, A, QKV_T / 4);
    qkv_proj_one<<<dim3(9, 64), 256, 0, stream>>>(Q, A, WT + 1L * E * E, b_in + E, K, 1, 0);
    // Q (which=0): two M-halves, hi/lo both in A slot
    presplit<<<2048, 256, 0, stream>>>(qin, A, A + HALF, HALF / 4);
    qkv_proj_one<<<dim3(9, 32), 256, 0, stream>>>(A, A + HALF, WT, b_in, Q, 0, 0);
    presplit<<<2048, 256, 0, stream>>>(qin + HALF, A, A + HALF, HALF / 4);
    qkv_proj_one<<<dim3(9, 32), 256, 0, stream>>>(A, A + HALF, WT, b_in, Q, 0, 4096);

    attn_fwd<<<dim3(8, 128), 256, 0, stream>>>(ws, A);
    wt_conv<<<dim3(36, 36), 256, 0, stream>>>(w_out, WTo, E, E);
    out_proj<<<dim3(9, 64), 256, 0, stream>>>(A, WTo, b_out, out);
}

// Round 8
// 462.934 us; speedup vs baseline: 1.1144x; 1.1144x over previous
//
#include <hip/hip_runtime.h>
#include <hip/hip_bf16.h>
#include <math.h>
#include <stdint.h>

// Problem constants
static constexpr int Bb = 8, S = 1024, E = 1152, H = 16, D = 72;
static constexpr int N3 = 3 * E;                 // 3456
static constexpr long QKV_T = (long)Bb * H * S * D;  // 9437184 elems per tensor

typedef __attribute__((ext_vector_type(8))) short bf16x8;
typedef __attribute__((ext_vector_type(4))) short bf16x4;
typedef __attribute__((ext_vector_type(4))) float f32x4;

#define MFMA16(A, B, C) __builtin_amdgcn_mfma_f32_16x16x32_bf16(A, B, C, 0, 0, 0)

__device__ __forceinline__ short f2bf(float f) {
    __hip_bfloat16 h = __float2bfloat16(f);
    return __builtin_bit_cast(short, h);
}
__device__ __forceinline__ float bf2f(short s) {
    unsigned u = ((unsigned)(unsigned short)s) << 16;
    return __builtin_bit_cast(float, u);
}
__device__ __forceinline__ unsigned packbf(float lo, float hi) {
    return (unsigned)(unsigned short)f2bf(lo) | ((unsigned)(unsigned short)f2bf(hi) << 16);
}

__device__ __forceinline__ void gload_lds16(const void* g, void* l) {
    __builtin_amdgcn_global_load_lds(
        (const __attribute__((address_space(1))) unsigned int*)g,
        (__attribute__((address_space(3))) unsigned int*)l, 16, 0, 0);
}

// ---------------------------------------------------------------------------
// Kernel A: transpose+convert.  W[K][N] f32 -> WT[N][K] bf16.
// ---------------------------------------------------------------------------
__global__ __launch_bounds__(256)
void wt_conv(const float* __restrict__ W, short* __restrict__ WT, int K, int N)
{
    __shared__ float tt[32][33];
    const int n0 = blockIdx.x * 32, k0 = blockIdx.y * 32;
    const int t = threadIdx.x;
    {
        int r = t >> 3, c4 = (t & 7) * 4;
        float4 v = *reinterpret_cast<const float4*>(W + (long)(k0 + r) * N + n0 + c4);
        tt[r][c4 + 0] = v.x; tt[r][c4 + 1] = v.y; tt[r][c4 + 2] = v.z; tt[r][c4 + 3] = v.w;
    }
    __syncthreads();
    {
        int n = t >> 3, k4 = (t & 7) * 4;
        bf16x4 o = {f2bf(tt[k4 + 0][n]), f2bf(tt[k4 + 1][n]),
                    f2bf(tt[k4 + 2][n]), f2bf(tt[k4 + 3][n])};
        *reinterpret_cast<bf16x4*>(WT + (long)(n0 + n) * K + k0 + k4) = o;
    }
}

// ---------------------------------------------------------------------------
// Kernel B: split f32 -> hi/lo bf16.  n4 = element_count / 4.
// ---------------------------------------------------------------------------
__global__ __launch_bounds__(256)
void presplit(const float* __restrict__ X, short* __restrict__ XH,
              short* __restrict__ XL, long n4)
{
    for (long i = (long)blockIdx.x * 256 + threadIdx.x; i < n4; i += (long)gridDim.x * 256) {
        float4 v = reinterpret_cast<const float4*>(X)[i];
        short h0 = f2bf(v.x), h1 = f2bf(v.y), h2 = f2bf(v.z), h3 = f2bf(v.w);
        bf16x4 hi = {h0, h1, h2, h3};
        bf16x4 lo = {f2bf(v.x - bf2f(h0)), f2bf(v.y - bf2f(h1)),
                     f2bf(v.z - bf2f(h2)), f2bf(v.w - bf2f(h3))};
        reinterpret_cast<bf16x4*>(XH)[i] = hi;
        reinterpret_cast<bf16x4*>(XL)[i] = lo;
    }
}

// ---------------------------------------------------------------------------
// Kernel 1: projection for ONE of q/k/v.  C[rows,1152] = X @ Wg + bg.
// 2-term split-bf16 (Ahi*B + Alo*B); full-wave global_load_lds staging only.
// which==2 (V): stored transposed [bh][d][s], chunk-swizzled within each
// 64-s block (chunk ^= d&7) so attn can gload linearly + XOR on read.
// ---------------------------------------------------------------------------
__global__ __launch_bounds__(256)
void qkv_proj_one(const short* __restrict__ XH, const short* __restrict__ XL,
                  const short* __restrict__ WTn, const float* __restrict__ bias,
                  short* __restrict__ qkvW, int which, int m_base)
{
    __shared__ short aHi[128][32], aLo[128][32], bW[128][32];
    const int tid = threadIdx.x, lane = tid & 63, w = tid >> 6;
    const int c = lane & 15, g = lane >> 4;
    const int m0 = blockIdx.y * 128, n0 = blockIdx.x * 128;
    const int wm = (w >> 1) * 64, wn = (w & 1) * 64;
    const int lrow = lane >> 2, lch = (lane & 3) * 8;

    f32x4 acc[4][4] = {};

    for (int k0 = 0; k0 < E; k0 += 32) {
        __syncthreads();
        for (int t = 0; t < 2; ++t) {
            int row = w * 32 + t * 16;
            gload_lds16(XH + (long)(m0 + row + lrow) * E + k0 + lch, &aHi[row][0]);
            gload_lds16(XL + (long)(m0 + row + lrow) * E + k0 + lch, &aLo[row][0]);
            gload_lds16(WTn + (long)(n0 + row + lrow) * E + k0 + lch, &bW[row][0]);
        }
        __syncthreads();

        bf16x8 ah[4], al[4], bh[4];
        for (int i = 0; i < 4; ++i) {
            ah[i] = *reinterpret_cast<const bf16x8*>(&aHi[wm + i * 16 + c][g * 8]);
            al[i] = *reinterpret_cast<const bf16x8*>(&aLo[wm + i * 16 + c][g * 8]);
            bh[i] = *reinterpret_cast<const bf16x8*>(&bW[wn + i * 16 + c][g * 8]);
        }
        for (int i = 0; i < 4; ++i)
            for (int j = 0; j < 4; ++j) {
                acc[i][j] = MFMA16(ah[i], bh[j], acc[i][j]);
                acc[i][j] = MFMA16(al[i], bh[j], acc[i][j]);
            }
    }

    for (int j = 0; j < 4; ++j) {
        int n = n0 + wn + j * 16 + c;      // 0..1151
        float bv = bias[n];
        int hh = n / D, dd = n % D;
        if (which < 2) {
            for (int i = 0; i < 4; ++i) {
                int rowb = m_base + m0 + wm + i * 16 + g * 4;
                for (int r = 0; r < 4; ++r) {
                    int row = rowb + r;
                    int b = row >> 10, s = row & 1023;
                    qkvW[((long)(b * H + hh) * S + s) * D + dd] = f2bf(acc[i][j][r] + bv);
                }
            }
        } else {
            int cx = dd & 7;
            for (int i = 0; i < 4; ++i) {
                int srow = m_base + m0 + wm + i * 16 + g * 4;   // 4 consecutive s
                int b = srow >> 10, s = srow & 1023;
                int sw = (s & ~63) | ((((s >> 3) & 7) ^ cx) << 3) | (s & 7);
                bf16x4 pk = {f2bf(acc[i][j][0] + bv), f2bf(acc[i][j][1] + bv),
                             f2bf(acc[i][j][2] + bv), f2bf(acc[i][j][3] + bv)};
                *reinterpret_cast<bf16x4*>(&qkvW[((long)(b * H + hh) * D + dd) * S + sw]) = pk;
            }
        }
    }
}

// ---------------------------------------------------------------------------
// Kernel 2: flash attention.  Swapped-operand (S^T = K Q^T -> in-lane softmax,
// O^T = V^T P^T) + coalesced gload_lds staging of K and pre-swizzled V^T.
// Grid (bh, qb): dispatch index ≡ bh (mod 8) -> all q-blocks of one (b,h)
// share an XCD's L2 copy of K/V.
// LDS (shorts): K[64][72]@0 | guard 24 @4608 | V[80][64]@4632 (rows 72.. zero)
//             | P dwords @9752.  Total 37936 B.
// ---------------------------------------------------------------------------
__global__ __launch_bounds__(256, 4)
void attn_fwd(const short* __restrict__ qkv, short* __restrict__ attn)
{
    __shared__ short smem[18968];
    unsigned* PT = reinterpret_cast<unsigned*>(smem + 9752);
    const int tid = threadIdx.x, lane = tid & 63, w = tid >> 6;
    const int c = lane & 15, g = lane >> 4;
    const int bh = blockIdx.x;
    const int q0 = blockIdx.y * 128;
    const int b = bh >> 4, h = bh & 15;

    const short* Qb = qkv + (long)bh * (S * D);
    const short* Kb = qkv + QKV_T + (long)bh * (S * D);
    const short* Vt = qkv + 2 * QKV_T + (long)bh * ((long)D * S);

    // zero: K guard (24 shorts) + V pad rows 72..79 (512 shorts)
    if (tid < 24) smem[4608 + tid] = 0;
    for (int i = tid; i < 512; i += 256) smem[4632 + 4608 + i] = 0;

    // staging descriptors (3 compile-time rounds; round r = w + rr*4, r < 9)
    // K chunks are exactly linear: addr = Kb + id*8 (72 shorts = 9 x 8)
    const short* kg[3]; const short* vg[3]; int ldsOff[3];
    #pragma unroll
    for (int rr = 0; rr < 3; ++rr) {
        int r = w + rr * 4;
        int id = r * 64 + lane;
        kg[rr] = Kb + id * 8;
        vg[rr] = Vt + (long)(id >> 3) * S + (id & 7) * 8;
        ldsOff[rr] = id * 8;
    }

    // Q fragments (B-operand), d-tail zero for g>0
    bf16x8 qf[2][3];
    const bf16x8 zf = {};
    for (int i = 0; i < 2; ++i) {
        const short* qr = Qb + (long)(q0 + w * 32 + i * 16 + c) * D;
        qf[i][0] = *reinterpret_cast<const bf16x8*>(qr + g * 8);
        qf[i][1] = *reinterpret_cast<const bf16x8*>(qr + 32 + g * 8);
        qf[i][2] = (g == 0) ? *reinterpret_cast<const bf16x8*>(qr + 64) : zf;
    }

    const float K2 = 0.17003594880664552f;   // 72^-0.5 * log2(e)
    float m_run[2] = {-1e30f, -1e30f}, l_run[2] = {0.f, 0.f};
    f32x4 accO[5][2] = {};

    for (int kt = 0; kt < 16; ++kt) {
        __syncthreads();   // prior tile's reads done
        #pragma unroll
        for (int rr = 0; rr < 3; ++rr) {
            if (w + rr * 4 < 9) {
                gload_lds16(kg[rr], &smem[ldsOff[rr]]);
                gload_lds16(vg[rr], &smem[4632 + ldsOff[rr]]);
                kg[rr] += 64 * D;
                vg[rr] += 64;
            }
        }
        __syncthreads();   // compiler drains vmcnt before barrier

        // ---- S^T[k'][q] = K Q^T ----
        f32x4 sT[4][2] = {};
        for (int dc = 0; dc < 3; ++dc) {
            for (int j = 0; j < 4; ++j) {
                bf16x8 kf = *reinterpret_cast<const bf16x8*>(
                    &smem[(j * 16 + c) * 72 + dc * 32 + g * 8]);
                for (int i = 0; i < 2; ++i)
                    sT[j][i] = MFMA16(kf, qf[i][dc], sT[j][i]);
            }
        }

        // ---- in-lane online softmax (one q-row per lane per i) ----
        for (int i = 0; i < 2; ++i) {
            float mx = -1e30f;
            for (int j = 0; j < 4; ++j)
                for (int r = 0; r < 4; ++r) mx = fmaxf(mx, sT[j][i][r]);
            mx = fmaxf(mx, __shfl_xor(mx, 16));
            mx = fmaxf(mx, __shfl_xor(mx, 32));
            float m_new = fmaxf(m_run[i], mx);
            float corr = exp2f((m_run[i] - m_new) * K2);
            float mh = m_new * K2;
            m_run[i] = m_new;
            float ps = 0.f;
            for (int j = 0; j < 4; ++j) {
                float p0 = exp2f(fmaf(sT[j][i][0], K2, -mh));
                float p1 = exp2f(fmaf(sT[j][i][1], K2, -mh));
                float p2 = exp2f(fmaf(sT[j][i][2], K2, -mh));
                float p3 = exp2f(fmaf(sT[j][i][3], K2, -mh));
                ps += (p0 + p1) + (p2 + p3);
                PT[((w * 2 + i) * 16 + c) * 36 + j * 8 + g * 2 + 0] = packbf(p0, p1);
                PT[((w * 2 + i) * 16 + c) * 36 + j * 8 + g * 2 + 1] = packbf(p2, p3);
            }
            ps += __shfl_xor(ps, 16);
            ps += __shfl_xor(ps, 32);
            l_run[i] = l_run[i] * corr + ps;
            for (int n = 0; n < 5; ++n)
                for (int r = 0; r < 4; ++r) accO[n][i][r] *= corr;
        }

        // ---- O^T[d][q] += V^T P^T  (V slot XOR matches storage swizzle) ----
        for (int ks = 0; ks < 2; ++ks) {
            bf16x8 pf[2];
            for (int i = 0; i < 2; ++i)
                pf[i] = *reinterpret_cast<const bf16x8*>(
                    &PT[((w * 2 + i) * 16 + c) * 36 + ks * 16 + g * 4]);
            for (int n = 0; n < 5; ++n) {
                bf16x8 vf = *reinterpret_cast<const bf16x8*>(
                    &smem[4632 + (n * 16 + c) * 64 + (((ks * 4 + g) ^ (c & 7))) * 8]);
                for (int i = 0; i < 2; ++i)
                    accO[n][i] = MFMA16(vf, pf[i], accO[n][i]);
            }
        }
    }

    // ---- epilogue: attn[q][h*72+d], mask d >= 72 ----
    for (int i = 0; i < 2; ++i) {
        float inv = 1.f / l_run[i];
        int q = q0 + w * 32 + i * 16 + c;
        for (int n = 0; n < 5; ++n) {
            int d0 = n * 16 + g * 4;
            if (d0 >= D) continue;
            bf16x4 pk = {f2bf(accO[n][i][0] * inv), f2bf(accO[n][i][1] * inv),
                         f2bf(accO[n][i][2] * inv), f2bf(accO[n][i][3] * inv)};
            *reinterpret_cast<bf16x4*>(attn + (long)(b * S + q) * E + h * D + d0) = pk;
        }
    }
}

// ---------------------------------------------------------------------------
// Kernel 3: out projection.  out[8192,1152] = attn(bf16) @ WTo(bf16) + b.
// ---------------------------------------------------------------------------
__global__ __launch_bounds__(256)
void out_proj(const short* __restrict__ Aat, const short* __restrict__ WTo,
              const float* __restrict__ bias, float* __restrict__ out)
{
    __shared__ short aT[128][32], bT[128][32];
    const int tid = threadIdx.x, lane = tid & 63, w = tid >> 6;
    const int c = lane & 15, g = lane >> 4;
    const int m0 = blockIdx.y * 128, n0 = blockIdx.x * 128;
    const int wm = (w >> 1) * 64, wn = (w & 1) * 64;
    const int lrow = lane >> 2, lch = (lane & 3) * 8;

    f32x4 acc[4][4] = {};
    for (int k0 = 0; k0 < E; k0 += 32) {
        __syncthreads();
        for (int t = 0; t < 2; ++t) {
            int row = w * 32 + t * 16;
            gload_lds16(Aat + (long)(m0 + row + lrow) * E + k0 + lch, &aT[row][0]);
            gload_lds16(WTo + (long)(n0 + row + lrow) * E + k0 + lch, &bT[row][0]);
        }
        __syncthreads();

        bf16x8 af[4], bf[4];
        for (int i = 0; i < 4; ++i) {
            af[i] = *reinterpret_cast<const bf16x8*>(&aT[wm + i * 16 + c][g * 8]);
            bf[i] = *reinterpret_cast<const bf16x8*>(&bT[wn + i * 16 + c][g * 8]);
        }
        for (int i = 0; i < 4; ++i)
            for (int j = 0; j < 4; ++j)
                acc[i][j] = MFMA16(af[i], bf[j], acc[i][j]);
    }

    for (int j = 0; j < 4; ++j) {
        int n = n0 + wn + j * 16 + c;
        float bv = bias[n];
        for (int i = 0; i < 4; ++i)
            for (int r = 0; r < 4; ++r) {
                int row = m0 + wm + i * 16 + g * 4 + r;
                out[(long)row * E + n] = acc[i][j][r] + bv;
            }
    }
}

// ---------------------------------------------------------------------------
// Workspace (shorts), peak 83.46 MB:
//   Q[QKV_T] | K[QKV_T] | V^T[QKV_T] | A[QKV_T] | WT[3456*1152]
// ---------------------------------------------------------------------------
extern "C" void kernel_launch(void* const* d_in, const int* in_sizes, int n_in,
                              void* d_out, int out_size, void* d_ws, size_t ws_size,
                              hipStream_t stream)
{
    const float* qin   = (const float*)d_in[0];
    const float* kin   = (const float*)d_in[1];
    const float* vin   = (const float*)d_in[2];
    const float* w_in  = (const float*)d_in[3];
    const float* b_in  = (const float*)d_in[4];
    const float* w_out = (const float*)d_in[5];
    const float* b_out = (const float*)d_in[6];

    short* ws  = (short*)d_ws;
    short* Q   = ws;
    short* K   = ws + QKV_T;
    short* V   = ws + 2 * QKV_T;
    short* A   = ws + 3 * QKV_T;
    short* WT  = ws + 4 * QKV_T;
    short* WTo = WT;
    float* out = (float*)d_out;
    const long HALF = QKV_T / 2;

    wt_conv<<<dim3(108, 36), 256, 0, stream>>>(w_in, WT, E, N3);

    // V (which=2): hi/lo in Q,K slots (free)
    presplit<<<2048, 256, 0, stream>>>(vin, Q, K, QKV_T / 4);
    qkv_proj_one<<<dim3(9, 64), 256, 0, stream>>>(Q, K, WT + 2L * E * E, b_in + 2 * E, V, 2, 0);
    // K (which=1): hi in Q slot, lo in A slot
    presplit<<<2048, 256, 0, stream>>>(kin, Q, A, QKV_T / 4);
    qkv_proj_one<<<dim3(9, 64), 256, 0, stream>>>(Q, A, WT + 1L * E * E, b_in + E, K, 1, 0);
    // Q (which=0): two M-halves, hi/lo both in A slot
    presplit<<<2048, 256, 0, stream>>>(qin, A, A + HALF, HALF / 4);
    qkv_proj_one<<<dim3(9, 32), 256, 0, stream>>>(A, A + HALF, WT, b_in, Q, 0, 0);
    presplit<<<2048, 256, 0, stream>>>(qin + HALF, A, A + HALF, HALF / 4);
    qkv_proj_one<<<dim3(9, 32), 256, 0, stream>>>(A, A + HALF, WT, b_in, Q, 0, 4096);

    attn_fwd<<<dim3(128, 8), 256, 0, stream>>>(ws, A);
    wt_conv<<<dim3(36, 36), 256, 0, stream>>>(w_out, WTo, E, E);
    out_proj<<<dim3(9, 64), 256, 0, stream>>>(A, WTo, b_out, out);
}

// Round 9
// 459.700 us; speedup vs baseline: 1.1222x; 1.0070x over previous
//
#include <hip/hip_runtime.h>
#include <hip/hip_bf16.h>
#include <math.h>
#include <stdint.h>

// Problem constants
static constexpr int Bb = 8, S = 1024, E = 1152, H = 16, D = 72;
static constexpr int N3 = 3 * E;                 // 3456
static constexpr long QKV_T = (long)Bb * H * S * D;  // 9437184 elems per tensor

typedef __attribute__((ext_vector_type(8))) short bf16x8;
typedef __attribute__((ext_vector_type(4))) short bf16x4;
typedef __attribute__((ext_vector_type(4))) float f32x4;

#define MFMA16(A, B, C) __builtin_amdgcn_mfma_f32_16x16x32_bf16(A, B, C, 0, 0, 0)

__device__ __forceinline__ short f2bf(float f) {
    __hip_bfloat16 h = __float2bfloat16(f);
    return __builtin_bit_cast(short, h);
}
__device__ __forceinline__ float bf2f(short s) {
    unsigned u = ((unsigned)(unsigned short)s) << 16;
    return __builtin_bit_cast(float, u);
}
__device__ __forceinline__ unsigned packbf(float lo, float hi) {
    return (unsigned)(unsigned short)f2bf(lo) | ((unsigned)(unsigned short)f2bf(hi) << 16);
}

__device__ __forceinline__ void gload_lds16(const void* g, void* l) {
    __builtin_amdgcn_global_load_lds(
        (const __attribute__((address_space(1))) unsigned int*)g,
        (__attribute__((address_space(3))) unsigned int*)l, 16, 0, 0);
}

// ---------------------------------------------------------------------------
// Kernel A: transpose+convert.  W[K][N] f32 -> WT[N][K] bf16.
// ---------------------------------------------------------------------------
__global__ __launch_bounds__(256)
void wt_conv(const float* __restrict__ W, short* __restrict__ WT, int K, int N)
{
    __shared__ float tt[32][33];
    const int n0 = blockIdx.x * 32, k0 = blockIdx.y * 32;
    const int t = threadIdx.x;
    {
        int r = t >> 3, c4 = (t & 7) * 4;
        float4 v = *reinterpret_cast<const float4*>(W + (long)(k0 + r) * N + n0 + c4);
        tt[r][c4 + 0] = v.x; tt[r][c4 + 1] = v.y; tt[r][c4 + 2] = v.z; tt[r][c4 + 3] = v.w;
    }
    __syncthreads();
    {
        int n = t >> 3, k4 = (t & 7) * 4;
        bf16x4 o = {f2bf(tt[k4 + 0][n]), f2bf(tt[k4 + 1][n]),
                    f2bf(tt[k4 + 2][n]), f2bf(tt[k4 + 3][n])};
        *reinterpret_cast<bf16x4*>(WT + (long)(n0 + n) * K + k0 + k4) = o;
    }
}

// ---------------------------------------------------------------------------
// Kernel B: split f32 -> hi/lo bf16.  n4 = element_count / 4.
// ---------------------------------------------------------------------------
__global__ __launch_bounds__(256)
void presplit(const float* __restrict__ X, short* __restrict__ XH,
              short* __restrict__ XL, long n4)
{
    for (long i = (long)blockIdx.x * 256 + threadIdx.x; i < n4; i += (long)gridDim.x * 256) {
        float4 v = reinterpret_cast<const float4*>(X)[i];
        short h0 = f2bf(v.x), h1 = f2bf(v.y), h2 = f2bf(v.z), h3 = f2bf(v.w);
        bf16x4 hi = {h0, h1, h2, h3};
        bf16x4 lo = {f2bf(v.x - bf2f(h0)), f2bf(v.y - bf2f(h1)),
                     f2bf(v.z - bf2f(h2)), f2bf(v.w - bf2f(h3))};
        reinterpret_cast<bf16x4*>(XH)[i] = hi;
        reinterpret_cast<bf16x4*>(XL)[i] = lo;
    }
}

// ---------------------------------------------------------------------------
// Kernel 1: projection for ONE of q/k/v.  C[rows,1152] = X @ Wg + bg.
// 2-term split-bf16 (Ahi*B + Alo*B); full-wave global_load_lds staging only.
// which==2 (V): stored transposed [bh][d][s], chunk-swizzled within each
// 64-s block (chunk ^= d&7) so attn can gload linearly + XOR on read.
// ---------------------------------------------------------------------------
__global__ __launch_bounds__(256)
void qkv_proj_one(const short* __restrict__ XH, const short* __restrict__ XL,
                  const short* __restrict__ WTn, const float* __restrict__ bias,
                  short* __restrict__ qkvW, int which, int m_base)
{
    __shared__ short aHi[128][32], aLo[128][32], bW[128][32];
    const int tid = threadIdx.x, lane = tid & 63, w = tid >> 6;
    const int c = lane & 15, g = lane >> 4;
    const int m0 = blockIdx.y * 128, n0 = blockIdx.x * 128;
    const int wm = (w >> 1) * 64, wn = (w & 1) * 64;
    const int lrow = lane >> 2, lch = (lane & 3) * 8;

    f32x4 acc[4][4] = {};

    for (int k0 = 0; k0 < E; k0 += 32) {
        __syncthreads();
        for (int t = 0; t < 2; ++t) {
            int row = w * 32 + t * 16;
            gload_lds16(XH + (long)(m0 + row + lrow) * E + k0 + lch, &aHi[row][0]);
            gload_lds16(XL + (long)(m0 + row + lrow) * E + k0 + lch, &aLo[row][0]);
            gload_lds16(WTn + (long)(n0 + row + lrow) * E + k0 + lch, &bW[row][0]);
        }
        __syncthreads();

        bf16x8 ah[4], al[4], bh[4];
        for (int i = 0; i < 4; ++i) {
            ah[i] = *reinterpret_cast<const bf16x8*>(&aHi[wm + i * 16 + c][g * 8]);
            al[i] = *reinterpret_cast<const bf16x8*>(&aLo[wm + i * 16 + c][g * 8]);
            bh[i] = *reinterpret_cast<const bf16x8*>(&bW[wn + i * 16 + c][g * 8]);
        }
        for (int i = 0; i < 4; ++i)
            for (int j = 0; j < 4; ++j) {
                acc[i][j] = MFMA16(ah[i], bh[j], acc[i][j]);
                acc[i][j] = MFMA16(al[i], bh[j], acc[i][j]);
            }
    }

    for (int j = 0; j < 4; ++j) {
        int n = n0 + wn + j * 16 + c;      // 0..1151
        float bv = bias[n];
        int hh = n / D, dd = n % D;
        if (which < 2) {
            for (int i = 0; i < 4; ++i) {
                int rowb = m_base + m0 + wm + i * 16 + g * 4;
                for (int r = 0; r < 4; ++r) {
                    int row = rowb + r;
                    int b = row >> 10, s = row & 1023;
                    qkvW[((long)(b * H + hh) * S + s) * D + dd] = f2bf(acc[i][j][r] + bv);
                }
            }
        } else {
            int cx = dd & 7;
            for (int i = 0; i < 4; ++i) {
                int srow = m_base + m0 + wm + i * 16 + g * 4;   // 4 consecutive s
                int b = srow >> 10, s = srow & 1023;
                int sw = (s & ~63) | ((((s >> 3) & 7) ^ cx) << 3) | (s & 7);
                bf16x4 pk = {f2bf(acc[i][j][0] + bv), f2bf(acc[i][j][1] + bv),
                             f2bf(acc[i][j][2] + bv), f2bf(acc[i][j][3] + bv)};
                *reinterpret_cast<bf16x4*>(&qkvW[((long)(b * H + hh) * D + dd) * S + sw]) = pk;
            }
        }
    }
}

// ---------------------------------------------------------------------------
// Kernel 2: flash attention.  Swapped-operand (S^T = K Q^T -> in-lane softmax,
// O^T = V^T P^T) + coalesced gload_lds staging of K and pre-swizzled V^T.
// Grid (bh, qb): all q-blocks of one (b,h) share an XCD's L2 copy of K/V.
// LDS (shorts): K[64][72]@0 | guard 24 @4608 | V[80][64]@4632 (rows 72.. zero)
//             | P dwords @9752.  Epilogue reuses smem[0..9216) as O[128][72]
// and writes contiguous 144-B row bursts (full-sector HBM writes, no RMW).
// ---------------------------------------------------------------------------
__global__ __launch_bounds__(256, 4)
void attn_fwd(const short* __restrict__ qkv, short* __restrict__ attn)
{
    __shared__ short smem[18968];
    unsigned* PT = reinterpret_cast<unsigned*>(smem + 9752);
    const int tid = threadIdx.x, lane = tid & 63, w = tid >> 6;
    const int c = lane & 15, g = lane >> 4;
    const int bh = blockIdx.x;
    const int q0 = blockIdx.y * 128;
    const int b = bh >> 4, h = bh & 15;

    const short* Qb = qkv + (long)bh * (S * D);
    const short* Kb = qkv + QKV_T + (long)bh * (S * D);
    const short* Vt = qkv + 2 * QKV_T + (long)bh * ((long)D * S);

    // zero: K guard (24 shorts) + V pad rows 72..79 (512 shorts)
    if (tid < 24) smem[4608 + tid] = 0;
    for (int i = tid; i < 512; i += 256) smem[4632 + 4608 + i] = 0;

    // staging descriptors (3 compile-time rounds; round r = w + rr*4, r < 9)
    const short* kg[3]; const short* vg[3]; int ldsOff[3];
    #pragma unroll
    for (int rr = 0; rr < 3; ++rr) {
        int r = w + rr * 4;
        int id = r * 64 + lane;
        kg[rr] = Kb + id * 8;
        vg[rr] = Vt + (long)(id >> 3) * S + (id & 7) * 8;
        ldsOff[rr] = id * 8;
    }

    // Q fragments (B-operand), d-tail zero for g>0
    bf16x8 qf[2][3];
    const bf16x8 zf = {};
    for (int i = 0; i < 2; ++i) {
        const short* qr = Qb + (long)(q0 + w * 32 + i * 16 + c) * D;
        qf[i][0] = *reinterpret_cast<const bf16x8*>(qr + g * 8);
        qf[i][1] = *reinterpret_cast<const bf16x8*>(qr + 32 + g * 8);
        qf[i][2] = (g == 0) ? *reinterpret_cast<const bf16x8*>(qr + 64) : zf;
    }

    const float K2 = 0.17003594880664552f;   // 72^-0.5 * log2(e)
    float m_run[2] = {-1e30f, -1e30f}, l_run[2] = {0.f, 0.f};
    f32x4 accO[5][2] = {};

    for (int kt = 0; kt < 16; ++kt) {
        __syncthreads();   // prior tile's reads done
        #pragma unroll
        for (int rr = 0; rr < 3; ++rr) {
            if (w + rr * 4 < 9) {
                gload_lds16(kg[rr], &smem[ldsOff[rr]]);
                gload_lds16(vg[rr], &smem[4632 + ldsOff[rr]]);
                kg[rr] += 64 * D;
                vg[rr] += 64;
            }
        }
        __syncthreads();   // compiler drains vmcnt before barrier

        // ---- S^T[k'][q] = K Q^T ----
        f32x4 sT[4][2] = {};
        for (int dc = 0; dc < 3; ++dc) {
            for (int j = 0; j < 4; ++j) {
                bf16x8 kf = *reinterpret_cast<const bf16x8*>(
                    &smem[(j * 16 + c) * 72 + dc * 32 + g * 8]);
                for (int i = 0; i < 2; ++i)
                    sT[j][i] = MFMA16(kf, qf[i][dc], sT[j][i]);
            }
        }

        // ---- in-lane online softmax (one q-row per lane per i) ----
        for (int i = 0; i < 2; ++i) {
            float mx = -1e30f;
            for (int j = 0; j < 4; ++j)
                for (int r = 0; r < 4; ++r) mx = fmaxf(mx, sT[j][i][r]);
            mx = fmaxf(mx, __shfl_xor(mx, 16));
            mx = fmaxf(mx, __shfl_xor(mx, 32));
            float m_new = fmaxf(m_run[i], mx);
            float corr = exp2f((m_run[i] - m_new) * K2);
            float mh = m_new * K2;
            m_run[i] = m_new;
            float ps = 0.f;
            for (int j = 0; j < 4; ++j) {
                float p0 = exp2f(fmaf(sT[j][i][0], K2, -mh));
                float p1 = exp2f(fmaf(sT[j][i][1], K2, -mh));
                float p2 = exp2f(fmaf(sT[j][i][2], K2, -mh));
                float p3 = exp2f(fmaf(sT[j][i][3], K2, -mh));
                ps += (p0 + p1) + (p2 + p3);
                PT[((w * 2 + i) * 16 + c) * 36 + j * 8 + g * 2 + 0] = packbf(p0, p1);
                PT[((w * 2 + i) * 16 + c) * 36 + j * 8 + g * 2 + 1] = packbf(p2, p3);
            }
            ps += __shfl_xor(ps, 16);
            ps += __shfl_xor(ps, 32);
            l_run[i] = l_run[i] * corr + ps;
            for (int n = 0; n < 5; ++n)
                for (int r = 0; r < 4; ++r) accO[n][i][r] *= corr;
        }

        // ---- O^T[d][q] += V^T P^T  (V slot XOR matches storage swizzle) ----
        for (int ks = 0; ks < 2; ++ks) {
            bf16x8 pf[2];
            for (int i = 0; i < 2; ++i)
                pf[i] = *reinterpret_cast<const bf16x8*>(
                    &PT[((w * 2 + i) * 16 + c) * 36 + ks * 16 + g * 4]);
            for (int n = 0; n < 5; ++n) {
                bf16x8 vf = *reinterpret_cast<const bf16x8*>(
                    &smem[4632 + (n * 16 + c) * 64 + (((ks * 4 + g) ^ (c & 7))) * 8]);
                for (int i = 0; i < 2; ++i)
                    accO[n][i] = MFMA16(vf, pf[i], accO[n][i]);
            }
        }
    }

    // ---- epilogue: stage O in LDS (reuse dead K/V space), then write
    //      contiguous 144-B row bursts ----
    __syncthreads();   // all waves done reading K/V LDS
    for (int i = 0; i < 2; ++i) {
        float inv = 1.f / l_run[i];
        int ql = w * 32 + i * 16 + c;          // 0..127
        for (int n = 0; n < 5; ++n) {
            int d0 = n * 16 + g * 4;
            if (d0 >= D) continue;
            bf16x4 pk = {f2bf(accO[n][i][0] * inv), f2bf(accO[n][i][1] * inv),
                         f2bf(accO[n][i][2] * inv), f2bf(accO[n][i][3] * inv)};
            *reinterpret_cast<bf16x4*>(&smem[ql * 72 + d0]) = pk;
        }
    }
    __syncthreads();
    {
        const long rowbase = (long)(b * S + q0) * E + h * D;
        for (int ch = tid; ch < 1152; ch += 256) {
            int row = ch / 9, off = (ch % 9) * 8;
            *reinterpret_cast<uint4*>(attn + rowbase + (long)row * E + off) =
                *reinterpret_cast<const uint4*>(&smem[row * 72 + off]);
        }
    }
}

// ---------------------------------------------------------------------------
// Kernel 3: out projection.  out[8192,1152] = attn(bf16) @ WTo(bf16) + b.
// ---------------------------------------------------------------------------
__global__ __launch_bounds__(256)
void out_proj(const short* __restrict__ Aat, const short* __restrict__ WTo,
              const float* __restrict__ bias, float* __restrict__ out)
{
    __shared__ short aT[128][32], bT[128][32];
    const int tid = threadIdx.x, lane = tid & 63, w = tid >> 6;
    const int c = lane & 15, g = lane >> 4;
    const int m0 = blockIdx.y * 128, n0 = blockIdx.x * 128;
    const int wm = (w >> 1) * 64, wn = (w & 1) * 64;
    const int lrow = lane >> 2, lch = (lane & 3) * 8;

    f32x4 acc[4][4] = {};
    for (int k0 = 0; k0 < E; k0 += 32) {
        __syncthreads();
        for (int t = 0; t < 2; ++t) {
            int row = w * 32 + t * 16;
            gload_lds16(Aat + (long)(m0 + row + lrow) * E + k0 + lch, &aT[row][0]);
            gload_lds16(WTo + (long)(n0 + row + lrow) * E + k0 + lch, &bT[row][0]);
        }
        __syncthreads();

        bf16x8 af[4], bf[4];
        for (int i = 0; i < 4; ++i) {
            af[i] = *reinterpret_cast<const bf16x8*>(&aT[wm + i * 16 + c][g * 8]);
            bf[i] = *reinterpret_cast<const bf16x8*>(&bT[wn + i * 16 + c][g * 8]);
        }
        for (int i = 0; i < 4; ++i)
            for (int j = 0; j < 4; ++j)
                acc[i][j] = MFMA16(af[i], bf[j], acc[i][j]);
    }

    for (int j = 0; j < 4; ++j) {
        int n = n0 + wn + j * 16 + c;
        float bv = bias[n];
        for (int i = 0; i < 4; ++i)
            for (int r = 0; r < 4; ++r) {
                int row = m0 + wm + i * 16 + g * 4 + r;
                out[(long)row * E + n] = acc[i][j][r] + bv;
            }
    }
}

// ---------------------------------------------------------------------------
// Workspace (shorts), peak 83.46 MB:
//   Q[QKV_T] | K[QKV_T] | V^T[QKV_T] | A[QKV_T] | WT[3456*1152]
// ---------------------------------------------------------------------------
extern "C" void kernel_launch(void* const* d_in, const int* in_sizes, int n_in,
                              void* d_out, int out_size, void* d_ws, size_t ws_size,
                              hipStream_t stream)
{
    const float* qin   = (const float*)d_in[0];
    const float* kin   = (const float*)d_in[1];
    const float* vin   = (const float*)d_in[2];
    const float* w_in  = (const float*)d_in[3];
    const float* b_in  = (const float*)d_in[4];
    const float* w_out = (const float*)d_in[5];
    const float* b_out = (const float*)d_in[6];

    short* ws  = (short*)d_ws;
    short* Q   = ws;
    short* K   = ws + QKV_T;
    short* V   = ws + 2 * QKV_T;
    short* A   = ws + 3 * QKV_T;
    short* WT  = ws + 4 * QKV_T;
    short* WTo = WT;
    float* out = (float*)d_out;
    const long HALF = QKV_T / 2;

    wt_conv<<<dim3(108, 36), 256, 0, stream>>>(w_in, WT, E, N3);

    // V (which=2): hi/lo in Q,K slots (free)
    presplit<<<2048, 256, 0, stream>>>(vin, Q, K, QKV_T / 4);
    qkv_proj_one<<<dim3(9, 64), 256, 0, stream>>>(Q, K, WT + 2L * E * E, b_in + 2 * E, V, 2, 0);
    // K (which=1): hi in Q slot, lo in A slot
    presplit<<<2048, 256, 0, stream>>>(kin, Q, A, QKV_T / 4);
    qkv_proj_one<<<dim3(9, 64), 256, 0, stream>>>(Q, A, WT + 1L * E * E, b_in + E, K, 1, 0);
    // Q (which=0): two M-halves, hi/lo both in A slot
    presplit<<<2048, 256, 0, stream>>>(qin, A, A + HALF, HALF / 4);
    qkv_proj_one<<<dim3(9, 32), 256, 0, stream>>>(A, A + HALF, WT, b_in, Q, 0, 0);
    presplit<<<2048, 256, 0, stream>>>(qin + HALF, A, A + HALF, HALF / 4);
    qkv_proj_one<<<dim3(9, 32), 256, 0, stream>>>(A, A + HALF, WT, b_in, Q, 0, 4096);

    attn_fwd<<<dim3(128, 8), 256, 0, stream>>>(ws, A);
    wt_conv<<<dim3(36, 36), 256, 0, stream>>>(w_out, WTo, E, E);
    out_proj<<<dim3(9, 64), 256, 0, stream>>>(A, WTo, b_out, out);
}

// Round 10
// 325.180 us; speedup vs baseline: 1.5865x; 1.4137x over previous
//
#include <hip/hip_runtime.h>
#include <hip/hip_bf16.h>
#include <math.h>
#include <stdint.h>

// Problem constants
static constexpr int Bb = 8, S = 1024, E = 1152, H = 16, D = 72;
static constexpr int N3 = 3 * E;                 // 3456
static constexpr long QKV_T = (long)Bb * H * S * D;  // 9437184 elems per tensor

typedef __attribute__((ext_vector_type(8))) short bf16x8;
typedef __attribute__((ext_vector_type(4))) short bf16x4;
typedef __attribute__((ext_vector_type(4))) float f32x4;

#define MFMA16(A, B, C) __builtin_amdgcn_mfma_f32_16x16x32_bf16(A, B, C, 0, 0, 0)

__device__ __forceinline__ short f2bf(float f) {
    __hip_bfloat16 h = __float2bfloat16(f);
    return __builtin_bit_cast(short, h);
}
__device__ __forceinline__ unsigned packbf(float lo, float hi) {
    return (unsigned)(unsigned short)f2bf(lo) | ((unsigned)(unsigned short)f2bf(hi) << 16);
}

__device__ __forceinline__ void gload_lds16(const void* g, void* l) {
    __builtin_amdgcn_global_load_lds(
        (const __attribute__((address_space(1))) unsigned int*)g,
        (__attribute__((address_space(3))) unsigned int*)l, 16, 0, 0);
}

// ---------------------------------------------------------------------------
// Kernel A: transpose+convert.  W[K][N] f32 -> WT[N][K] bf16.
// ---------------------------------------------------------------------------
__global__ __launch_bounds__(256)
void wt_conv(const float* __restrict__ W, short* __restrict__ WT, int K, int N)
{
    __shared__ float tt[32][33];
    const int n0 = blockIdx.x * 32, k0 = blockIdx.y * 32;
    const int t = threadIdx.x;
    {
        int r = t >> 3, c4 = (t & 7) * 4;
        float4 v = *reinterpret_cast<const float4*>(W + (long)(k0 + r) * N + n0 + c4);
        tt[r][c4 + 0] = v.x; tt[r][c4 + 1] = v.y; tt[r][c4 + 2] = v.z; tt[r][c4 + 3] = v.w;
    }
    __syncthreads();
    {
        int n = t >> 3, k4 = (t & 7) * 4;
        bf16x4 o = {f2bf(tt[k4 + 0][n]), f2bf(tt[k4 + 1][n]),
                    f2bf(tt[k4 + 2][n]), f2bf(tt[k4 + 3][n])};
        *reinterpret_cast<bf16x4*>(WT + (long)(n0 + n) * K + k0 + k4) = o;
    }
}

// ---------------------------------------------------------------------------
// Kernel B: convert f32 -> bf16.  n4 = element_count / 4.
// ---------------------------------------------------------------------------
__global__ __launch_bounds__(256)
void tobf16(const float* __restrict__ X, short* __restrict__ Y, long n4)
{
    for (long i = (long)blockIdx.x * 256 + threadIdx.x; i < n4; i += (long)gridDim.x * 256) {
        float4 v = reinterpret_cast<const float4*>(X)[i];
        bf16x4 o = {f2bf(v.x), f2bf(v.y), f2bf(v.z), f2bf(v.w)};
        reinterpret_cast<bf16x4*>(Y)[i] = o;
    }
}

// ---------------------------------------------------------------------------
// Kernel 1: projection for ONE of q/k/v.  C[8192,1152] = X(bf16) @ Wg + bg.
// Plain bf16 MFMA (error analysis r9: A-lo term contributes <1e-3 at output,
// below the bf16 attn-chain floor).  All staging full-wave global_load_lds.
// which==2 (V): stored transposed [bh][d][s], chunk-swizzled within each
// 64-s block (chunk ^= d&7) so attn can gload linearly + XOR on read.
// ---------------------------------------------------------------------------
__global__ __launch_bounds__(256)
void qkv_proj_one(const short* __restrict__ Xb, const short* __restrict__ WTn,
                  const float* __restrict__ bias, short* __restrict__ qkvW, int which)
{
    __shared__ short aT[128][32], bW[128][32];
    const int tid = threadIdx.x, lane = tid & 63, w = tid >> 6;
    const int c = lane & 15, g = lane >> 4;
    const int m0 = blockIdx.y * 128, n0 = blockIdx.x * 128;
    const int wm = (w >> 1) * 64, wn = (w & 1) * 64;
    const int lrow = lane >> 2, lch = (lane & 3) * 8;

    f32x4 acc[4][4] = {};

    for (int k0 = 0; k0 < E; k0 += 32) {
        __syncthreads();
        for (int t = 0; t < 2; ++t) {
            int row = w * 32 + t * 16;
            gload_lds16(Xb + (long)(m0 + row + lrow) * E + k0 + lch, &aT[row][0]);
            gload_lds16(WTn + (long)(n0 + row + lrow) * E + k0 + lch, &bW[row][0]);
        }
        __syncthreads();

        bf16x8 af[4], bh[4];
        for (int i = 0; i < 4; ++i) {
            af[i] = *reinterpret_cast<const bf16x8*>(&aT[wm + i * 16 + c][g * 8]);
            bh[i] = *reinterpret_cast<const bf16x8*>(&bW[wn + i * 16 + c][g * 8]);
        }
        for (int i = 0; i < 4; ++i)
            for (int j = 0; j < 4; ++j)
                acc[i][j] = MFMA16(af[i], bh[j], acc[i][j]);
    }

    for (int j = 0; j < 4; ++j) {
        int n = n0 + wn + j * 16 + c;      // 0..1151
        float bv = bias[n];
        int hh = n / D, dd = n % D;
        if (which < 2) {
            for (int i = 0; i < 4; ++i) {
                int rowb = m0 + wm + i * 16 + g * 4;
                for (int r = 0; r < 4; ++r) {
                    int row = rowb + r;
                    int b = row >> 10, s = row & 1023;
                    qkvW[((long)(b * H + hh) * S + s) * D + dd] = f2bf(acc[i][j][r] + bv);
                }
            }
        } else {
            int cx = dd & 7;
            for (int i = 0; i < 4; ++i) {
                int srow = m0 + wm + i * 16 + g * 4;   // 4 consecutive s
                int b = srow >> 10, s = srow & 1023;
                int sw = (s & ~63) | ((((s >> 3) & 7) ^ cx) << 3) | (s & 7);
                bf16x4 pk = {f2bf(acc[i][j][0] + bv), f2bf(acc[i][j][1] + bv),
                             f2bf(acc[i][j][2] + bv), f2bf(acc[i][j][3] + bv)};
                *reinterpret_cast<bf16x4*>(&qkvW[((long)(b * H + hh) * D + dd) * S + sw]) = pk;
            }
        }
    }
}

// ---------------------------------------------------------------------------
// Kernel 2: flash attention.  Swapped-operand (S^T = K Q^T -> in-lane softmax,
// O^T = V^T P^T) + coalesced gload_lds staging of K and pre-swizzled V^T.
// Grid (bh, qb): all q-blocks of one (b,h) share an XCD's L2 copy of K/V.
// LDS (shorts): K[64][72]@0 | guard 24 @4608 | V[80][64]@4632 (rows 72.. zero)
//             | P dwords @9752.  Epilogue reuses smem[0..9216) as O[128][72]
// and writes contiguous 144-B row bursts.
// ---------------------------------------------------------------------------
__global__ __launch_bounds__(256, 4)
void attn_fwd(const short* __restrict__ qkv, short* __restrict__ attn)
{
    __shared__ short smem[18968];
    unsigned* PT = reinterpret_cast<unsigned*>(smem + 9752);
    const int tid = threadIdx.x, lane = tid & 63, w = tid >> 6;
    const int c = lane & 15, g = lane >> 4;
    const int bh = blockIdx.x;
    const int q0 = blockIdx.y * 128;
    const int b = bh >> 4, h = bh & 15;

    const short* Qb = qkv + (long)bh * (S * D);
    const short* Kb = qkv + QKV_T + (long)bh * (S * D);
    const short* Vt = qkv + 2 * QKV_T + (long)bh * ((long)D * S);

    // zero: K guard (24 shorts) + V pad rows 72..79 (512 shorts)
    if (tid < 24) smem[4608 + tid] = 0;
    for (int i = tid; i < 512; i += 256) smem[4632 + 4608 + i] = 0;

    // staging descriptors (3 compile-time rounds; round r = w + rr*4, r < 9)
    const short* kg[3]; const short* vg[3]; int ldsOff[3];
    #pragma unroll
    for (int rr = 0; rr < 3; ++rr) {
        int r = w + rr * 4;
        int id = r * 64 + lane;
        kg[rr] = Kb + id * 8;
        vg[rr] = Vt + (long)(id >> 3) * S + (id & 7) * 8;
        ldsOff[rr] = id * 8;
    }

    // Q fragments (B-operand), d-tail zero for g>0
    bf16x8 qf[2][3];
    const bf16x8 zf = {};
    for (int i = 0; i < 2; ++i) {
        const short* qr = Qb + (long)(q0 + w * 32 + i * 16 + c) * D;
        qf[i][0] = *reinterpret_cast<const bf16x8*>(qr + g * 8);
        qf[i][1] = *reinterpret_cast<const bf16x8*>(qr + 32 + g * 8);
        qf[i][2] = (g == 0) ? *reinterpret_cast<const bf16x8*>(qr + 64) : zf;
    }

    const float K2 = 0.17003594880664552f;   // 72^-0.5 * log2(e)
    float m_run[2] = {-1e30f, -1e30f}, l_run[2] = {0.f, 0.f};
    f32x4 accO[5][2] = {};

    for (int kt = 0; kt < 16; ++kt) {
        __syncthreads();   // prior tile's reads done
        #pragma unroll
        for (int rr = 0; rr < 3; ++rr) {
            if (w + rr * 4 < 9) {
                gload_lds16(kg[rr], &smem[ldsOff[rr]]);
                gload_lds16(vg[rr], &smem[4632 + ldsOff[rr]]);
                kg[rr] += 64 * D;
                vg[rr] += 64;
            }
        }
        __syncthreads();   // compiler drains vmcnt before barrier

        // ---- S^T[k'][q] = K Q^T ----
        f32x4 sT[4][2] = {};
        for (int dc = 0; dc < 3; ++dc) {
            for (int j = 0; j < 4; ++j) {
                bf16x8 kf = *reinterpret_cast<const bf16x8*>(
                    &smem[(j * 16 + c) * 72 + dc * 32 + g * 8]);
                for (int i = 0; i < 2; ++i)
                    sT[j][i] = MFMA16(kf, qf[i][dc], sT[j][i]);
            }
        }

        // ---- in-lane online softmax (one q-row per lane per i) ----
        for (int i = 0; i < 2; ++i) {
            float mx = -1e30f;
            for (int j = 0; j < 4; ++j)
                for (int r = 0; r < 4; ++r) mx = fmaxf(mx, sT[j][i][r]);
            mx = fmaxf(mx, __shfl_xor(mx, 16));
            mx = fmaxf(mx, __shfl_xor(mx, 32));
            float m_new = fmaxf(m_run[i], mx);
            float corr = exp2f((m_run[i] - m_new) * K2);
            float mh = m_new * K2;
            m_run[i] = m_new;
            float ps = 0.f;
            for (int j = 0; j < 4; ++j) {
                float p0 = exp2f(fmaf(sT[j][i][0], K2, -mh));
                float p1 = exp2f(fmaf(sT[j][i][1], K2, -mh));
                float p2 = exp2f(fmaf(sT[j][i][2], K2, -mh));
                float p3 = exp2f(fmaf(sT[j][i][3], K2, -mh));
                ps += (p0 + p1) + (p2 + p3);
                PT[((w * 2 + i) * 16 + c) * 36 + j * 8 + g * 2 + 0] = packbf(p0, p1);
                PT[((w * 2 + i) * 16 + c) * 36 + j * 8 + g * 2 + 1] = packbf(p2, p3);
            }
            ps += __shfl_xor(ps, 16);
            ps += __shfl_xor(ps, 32);
            l_run[i] = l_run[i] * corr + ps;
            for (int n = 0; n < 5; ++n)
                for (int r = 0; r < 4; ++r) accO[n][i][r] *= corr;
        }

        // ---- O^T[d][q] += V^T P^T  (V slot XOR matches storage swizzle) ----
        for (int ks = 0; ks < 2; ++ks) {
            bf16x8 pf[2];
            for (int i = 0; i < 2; ++i)
                pf[i] = *reinterpret_cast<const bf16x8*>(
                    &PT[((w * 2 + i) * 16 + c) * 36 + ks * 16 + g * 4]);
            for (int n = 0; n < 5; ++n) {
                bf16x8 vf = *reinterpret_cast<const bf16x8*>(
                    &smem[4632 + (n * 16 + c) * 64 + (((ks * 4 + g) ^ (c & 7))) * 8]);
                for (int i = 0; i < 2; ++i)
                    accO[n][i] = MFMA16(vf, pf[i], accO[n][i]);
            }
        }
    }

    // ---- epilogue: stage O in LDS (reuse dead K/V space), then write
    //      contiguous 144-B row bursts ----
    __syncthreads();   // all waves done reading K/V LDS
    for (int i = 0; i < 2; ++i) {
        float inv = 1.f / l_run[i];
        int ql = w * 32 + i * 16 + c;          // 0..127
        for (int n = 0; n < 5; ++n) {
            int d0 = n * 16 + g * 4;
            if (d0 >= D) continue;
            bf16x4 pk = {f2bf(accO[n][i][0] * inv), f2bf(accO[n][i][1] * inv),
                         f2bf(accO[n][i][2] * inv), f2bf(accO[n][i][3] * inv)};
            *reinterpret_cast<bf16x4*>(&smem[ql * 72 + d0]) = pk;
        }
    }
    __syncthreads();
    {
        const long rowbase = (long)(b * S + q0) * E + h * D;
        for (int ch = tid; ch < 1152; ch += 256) {
            int row = ch / 9, off = (ch % 9) * 8;
            *reinterpret_cast<uint4*>(attn + rowbase + (long)row * E + off) =
                *reinterpret_cast<const uint4*>(&smem[row * 72 + off]);
        }
    }
}

// ---------------------------------------------------------------------------
// Kernel 3: out projection.  out[8192,1152] = attn(bf16) @ WTo(bf16) + b.
// ---------------------------------------------------------------------------
__global__ __launch_bounds__(256)
void out_proj(const short* __restrict__ Aat, const short* __restrict__ WTo,
              const float* __restrict__ bias, float* __restrict__ out)
{
    __shared__ short aT[128][32], bT[128][32];
    const int tid = threadIdx.x, lane = tid & 63, w = tid >> 6;
    const int c = lane & 15, g = lane >> 4;
    const int m0 = blockIdx.y * 128, n0 = blockIdx.x * 128;
    const int wm = (w >> 1) * 64, wn = (w & 1) * 64;
    const int lrow = lane >> 2, lch = (lane & 3) * 8;

    f32x4 acc[4][4] = {};
    for (int k0 = 0; k0 < E; k0 += 32) {
        __syncthreads();
        for (int t = 0; t < 2; ++t) {
            int row = w * 32 + t * 16;
            gload_lds16(Aat + (long)(m0 + row + lrow) * E + k0 + lch, &aT[row][0]);
            gload_lds16(WTo + (long)(n0 + row + lrow) * E + k0 + lch, &bT[row][0]);
        }
        __syncthreads();

        bf16x8 af[4], bf[4];
        for (int i = 0; i < 4; ++i) {
            af[i] = *reinterpret_cast<const bf16x8*>(&aT[wm + i * 16 + c][g * 8]);
            bf[i] = *reinterpret_cast<const bf16x8*>(&bT[wn + i * 16 + c][g * 8]);
        }
        for (int i = 0; i < 4; ++i)
            for (int j = 0; j < 4; ++j)
                acc[i][j] = MFMA16(af[i], bf[j], acc[i][j]);
    }

    for (int j = 0; j < 4; ++j) {
        int n = n0 + wn + j * 16 + c;
        float bv = bias[n];
        for (int i = 0; i < 4; ++i)
            for (int r = 0; r < 4; ++r) {
                int row = m0 + wm + i * 16 + g * 4 + r;
                out[(long)row * E + n] = acc[i][j][r] + bv;
            }
    }
}

// ---------------------------------------------------------------------------
// Workspace (shorts), peak 83.46 MB:
//   Q[QKV_T] | K[QKV_T] | V^T[QKV_T] | A[QKV_T] | WT[3456*1152]
// A slot holds the bf16-converted input during projections (dead after),
// then the attention output.  WTo aliases WT after projections.
// ---------------------------------------------------------------------------
extern "C" void kernel_launch(void* const* d_in, const int* in_sizes, int n_in,
                              void* d_out, int out_size, void* d_ws, size_t ws_size,
                              hipStream_t stream)
{
    const float* qin   = (const float*)d_in[0];
    const float* kin   = (const float*)d_in[1];
    const float* vin   = (const float*)d_in[2];
    const float* w_in  = (const float*)d_in[3];
    const float* b_in  = (const float*)d_in[4];
    const float* w_out = (const float*)d_in[5];
    const float* b_out = (const float*)d_in[6];

    short* ws  = (short*)d_ws;
    short* Q   = ws;
    short* K   = ws + QKV_T;
    short* V   = ws + 2 * QKV_T;
    short* A   = ws + 3 * QKV_T;   // converted input, then attn output
    short* WT  = ws + 4 * QKV_T;
    short* WTo = WT;
    float* out = (float*)d_out;

    wt_conv<<<dim3(108, 36), 256, 0, stream>>>(w_in, WT, E, N3);

    tobf16<<<2048, 256, 0, stream>>>(vin, A, QKV_T / 4);
    qkv_proj_one<<<dim3(9, 64), 256, 0, stream>>>(A, WT + 2L * E * E, b_in + 2 * E, V, 2);
    tobf16<<<2048, 256, 0, stream>>>(kin, A, QKV_T / 4);
    qkv_proj_one<<<dim3(9, 64), 256, 0, stream>>>(A, WT + 1L * E * E, b_in + E, K, 1);
    tobf16<<<2048, 256, 0, stream>>>(qin, A, QKV_T / 4);
    qkv_proj_one<<<dim3(9, 64), 256, 0, stream>>>(A, WT, b_in, Q, 0);

    attn_fwd<<<dim3(128, 8), 256, 0, stream>>>(ws, A);
    wt_conv<<<dim3(36, 36), 256, 0, stream>>>(w_out, WTo, E, E);
    out_proj<<<dim3(9, 64), 256, 0, stream>>>(A, WTo, b_out, out);
}